// Round 1
// 257.267 us; speedup vs baseline: 1.0906x; 1.0906x over previous
//
#include <hip/hip_runtime.h>
#include <hip/hip_bf16.h>

// LightGCN on MI355X. R13: p2 XCD-grouped segment swizzle + 4-edge ILP.
// R12 post-mortem: p2 flat at ~45 us across BP=1024->2048 (not parallelism
// bound); WRITE_SIZE stable at 48.4 MB = 3.02x ideal (16 MB). Theory: runs
// per (block,bucket) avg 27 B, ~2.3 runs/64B-line, adjacent runs written by
// blocks on DIFFERENT XCDs (round-robin dispatch) -> per-XCD L2s each evict
// a partial line (fill+writeback) -> 3x amp. Also VGPR_Count=8: compiler
// fully serialized the edge loop (no ILP).
// R13: (1) p2 block b processes segment blk=(b&7)*256+(b>>3) so adjacent
//          segments (adjacent part-positions) are same-XCD, near-concurrent
//          -> partial lines merge in one L2 before eviction;
//      (2) seg rounded to x4 (977->980); each thread owns 4 consecutive
//          edges, int4/float4 loads, 4 independent atomic+store chains.
// Predicted: p2 WRITE 48.4->~20 MB, FETCH 22->~18 MB, dur 45->~25 us.
// Falsification: WRITE drops but dur flat -> latency-bound -> R14 =
// transposed blockHist cursor load (write it from scanA) + LDS-staged flush.
//
// d_ws (4B units): embA bf16[totalF] | embB bf16[totalF] | Ub[B*64] |
//   Ib[B*64] | pairs int2[E] | part int2[E] | rowPtr[N+1] |
//   blockHist[NBMAX*BP] | bucketTotal[NBMAX] | bucketBase[NBMAX+1] |
//   flag2[N] | flagB[N]   (~79 MB; 95 MB proven available)

#define EMB 64
#define BSZ 512         // rows per bucket (pow2: lr = r&511, u = r>>9)
#define NBMAX 512       // max buckets (actual: ceil(150000/512)=293)
#define BP 2048         // partition blocks (edge segments)

__device__ __forceinline__ float bf2f_lo(unsigned int u) {
    return __int_as_float((int)(u << 16));
}
__device__ __forceinline__ float bf2f_hi(unsigned int u) {
    return __int_as_float((int)(u & 0xFFFF0000u));
}
__device__ __forceinline__ float bf2f(unsigned short u) {
    return __int_as_float(((int)u) << 16);
}
__device__ __forceinline__ unsigned short f2bf(float f) {
    union { float f; unsigned int i; } v;
    v.f = f;
    unsigned int lsb = (v.i >> 16) & 1;
    v.i += 0x7fffu + lsb;          // round-to-nearest-even
    return (unsigned short)(v.i >> 16);
}
__device__ __forceinline__ unsigned int pack2(float a, float b) {
    return (unsigned int)f2bf(a) | ((unsigned int)f2bf(b) << 16);
}

// inclusive scan across a 64-lane wave (no barriers)
__device__ __forceinline__ int wave_iscan(int v) {
    int lane = threadIdx.x & 63;
#pragma unroll
    for (int off = 1; off < 64; off <<= 1) {
        int x = __shfl_up(v, off, 64);
        if (lane >= off) v += x;
    }
    return v;
}

// ---------- fused: init (concat->bf16, zero flags) | p1 (bucket hist) -----
// blocks [0, initBlocks): init; [initBlocks, initBlocks+BP): p1.
__global__ void ALGN_init_p1(const float4* __restrict__ ue, const float4* __restrict__ ie,
                             uint4* __restrict__ emb, int* __restrict__ flags, int nFlags,
                             int nUser8, int n8, int initBlocks,
                             const int* __restrict__ rows, int* __restrict__ blockHist,
                             int nE, int seg, int nBuckets) {
    __shared__ int h[NBMAX];
    if (blockIdx.x < initBlocks) {
        int t = blockIdx.x * blockDim.x + threadIdx.x;
        if (t < nFlags) flags[t] = 0;
        if (t >= n8) return;
        float4 a, b;
        if (t < nUser8) { a = ue[2 * t]; b = ue[2 * t + 1]; }
        else           { a = ie[2 * (t - nUser8)]; b = ie[2 * (t - nUser8) + 1]; }
        uint4 o;
        o.x = pack2(a.x, a.y);
        o.y = pack2(a.z, a.w);
        o.z = pack2(b.x, b.y);
        o.w = pack2(b.z, b.w);
        emb[t] = o;
    } else {
        int blk = blockIdx.x - initBlocks;
        for (int i = threadIdx.x; i < nBuckets; i += blockDim.x) h[i] = 0;
        __syncthreads();
        int beg = blk * seg, end = min(beg + seg, nE);
        for (int e = beg + threadIdx.x; e < end; e += blockDim.x)
            atomicAdd(&h[rows[e] >> 9], 1);
        __syncthreads();
        for (int u = threadIdx.x; u < nBuckets; u += blockDim.x)
            blockHist[u * BP + blk] = h[u];      // bucket-major
    }
}

// ---------- scanA: per bucket, exclusive scan across BP=2048 blocks -------
// blockDim = 1024, 2 elements/thread; wave-shfl scan.
__global__ void ALGN_scanA(int* __restrict__ blockHist, int* __restrict__ bucketTotal) {
    __shared__ int wsum[16];
    int b = blockIdx.x, t = threadIdx.x;
    int wid = t >> 6;
    int v0 = blockHist[b * BP + 2 * t];
    int v1 = blockHist[b * BP + 2 * t + 1];
    int s = v0 + v1;
    int isc = wave_iscan(s);
    if ((t & 63) == 63) wsum[wid] = isc;
    __syncthreads();
    if (t < 64) {
        int x = (t < 16) ? wsum[t] : 0;
        x = wave_iscan(x);
        if (t < 16) wsum[t] = x;
    }
    __syncthreads();
    int incl = isc + ((wid > 0) ? wsum[wid - 1] : 0);
    int excl = incl - s;
    blockHist[b * BP + 2 * t]     = excl;        // exclusive over blocks
    blockHist[b * BP + 2 * t + 1] = excl + v0;
    if (t == 1023) bucketTotal[b] = incl;
}

// ---------- scanB: exclusive scan of bucket totals -> bases ----------
// blockDim = 512 (8 waves).
__global__ void ALGN_scanB(const int* __restrict__ bucketTotal, int* __restrict__ bucketBase,
                           int nBuckets) {
    __shared__ int wsum[8];
    int t = threadIdx.x;
    int wid = t >> 6;
    int v = (t < nBuckets) ? bucketTotal[t] : 0;
    int isc = wave_iscan(v);
    if ((t & 63) == 63) wsum[wid] = isc;
    __syncthreads();
    if (t < 64) {
        int s = (t < 8) ? wsum[t] : 0;
        s = wave_iscan(s);
        if (t < 8) wsum[t] = s;
    }
    __syncthreads();
    int incl = isc + ((wid > 0) ? wsum[wid - 1] : 0);
    if (t < nBuckets) bucketBase[t] = incl - v;
    if (t == nBuckets - 1) bucketBase[nBuckets] = incl;
}

// ---------- partition pass 2: scatter packed records, LDS cursors ----------
// record: x = (localRow<<18) | col  (localRow<512, col<2^18), y = val bits
// R13: blk = XCD-grouped swizzle of blockIdx (adjacent segments -> same XCD
// L2 so adjacent part-position runs merge before eviction); 4 consecutive
// edges per thread with int4/float4 loads (seg is x4-aligned -> 16B aligned).
__global__ void ALGN_p2(const int* __restrict__ rows, const int* __restrict__ cols,
                        const float* __restrict__ vals,
                        const int* __restrict__ blockHist, const int* __restrict__ bucketBase,
                        int2* __restrict__ part, int nE, int seg, int nBuckets) {
    __shared__ int cur[NBMAX];
    int blk = ((blockIdx.x & 7) * (BP >> 3)) + (blockIdx.x >> 3);
    for (int u = threadIdx.x; u < nBuckets; u += blockDim.x)
        cur[u] = bucketBase[u] + blockHist[u * BP + blk];
    __syncthreads();
    int beg = blk * seg, end = min(beg + seg, nE);
    for (int e = beg + (threadIdx.x << 2); e < end; e += (blockDim.x << 2)) {
        if (e + 4 <= end) {
            int4   r = *(const int4*)(rows + e);
            int4   c = *(const int4*)(cols + e);
            float4 v = *(const float4*)(vals + e);
            int p0 = atomicAdd(&cur[r.x >> 9], 1);
            int p1 = atomicAdd(&cur[r.y >> 9], 1);
            int p2 = atomicAdd(&cur[r.z >> 9], 1);
            int p3 = atomicAdd(&cur[r.w >> 9], 1);
            part[p0] = make_int2(((r.x & 511) << 18) | c.x, __float_as_int(v.x));
            part[p1] = make_int2(((r.y & 511) << 18) | c.y, __float_as_int(v.y));
            part[p2] = make_int2(((r.z & 511) << 18) | c.z, __float_as_int(v.z));
            part[p3] = make_int2(((r.w & 511) << 18) | c.w, __float_as_int(v.w));
        } else {
            for (int k = e; k < end; ++k) {
                int rr = rows[k];
                int pos = atomicAdd(&cur[rr >> 9], 1);
                part[pos] = make_int2(((rr & 511) << 18) | cols[k], __float_as_int(vals[k]));
            }
        }
    }
}

// ---------- per-bucket counting sort -> rowPtr + row-sorted pairs ----------
// blockDim = 1024; BSZ=512 local rows; wave-shfl scan.
__global__ void ALGN_bsort(const int2* __restrict__ part, const int* __restrict__ bucketBase,
                           int2* __restrict__ pairs, int* __restrict__ rowPtr,
                           int nNodes, int nBuckets, int nE) {
    __shared__ int st[BSZ];
    __shared__ int wsum[8];
    int b = blockIdx.x, t = threadIdx.x;
    int base = bucketBase[b], lim = bucketBase[b + 1];
    if (t < BSZ) st[t] = 0;
    __syncthreads();
    for (int j = base + t; j < lim; j += blockDim.x)
        atomicAdd(&st[part[j].x >> 18], 1);
    __syncthreads();
    int wid = t >> 6;
    int v = (t < BSZ) ? st[t] : 0;
    int isc = wave_iscan(v);
    if ((t & 63) == 63 && wid < 8) wsum[wid] = isc;
    __syncthreads();
    if (t < 64) {
        int s = (t < 8) ? wsum[t] : 0;
        s = wave_iscan(s);
        if (t < 8) wsum[t] = s;
    }
    __syncthreads();
    int excl = isc - v + ((wid > 0 && wid < 8) ? wsum[wid - 1] : 0);
    __syncthreads();
    if (t < BSZ) st[t] = excl;                   // exclusive starts / cursors
    int row = b * BSZ + t;
    if (t < BSZ && row < nNodes) rowPtr[row] = base + excl;
    if (b == nBuckets - 1 && t == 0) rowPtr[nNodes] = nE;
    __syncthreads();
    for (int j = base + t; j < lim; j += blockDim.x) {
        int2 p = part[j];
        int lr = p.x >> 18;
        int pos = base + atomicAdd(&st[lr], 1);
        pairs[pos] = make_int2(p.x & 0x3FFFF, p.y);
    }
}

// ---------- fused: mark2 (demand flags) | gather_set (layer 0) ----------
// blocks [0, markBlocks): mark2 (16 lanes/batch row);
// [markBlocks, markBlocks+gsBlocks): gather_set.
__global__ void ALGN_mark_gather(const int* __restrict__ rowPtr, const int2* __restrict__ pairs,
                                 const int* __restrict__ users, const int* __restrict__ items,
                                 int* __restrict__ flag2, int* __restrict__ flagB,
                                 int batch, int nUser, int markBlocks,
                                 const unsigned short* __restrict__ emb,
                                 float* __restrict__ U, float* __restrict__ I) {
    if (blockIdx.x < markBlocks) {
        int tid = blockIdx.x * blockDim.x + threadIdx.x;
        int idx = tid >> 4;
        int ln  = tid & 15;
        if (idx >= 2 * batch) return;
        int row = (idx < batch) ? users[idx] : (nUser + items[idx - batch]);
        if (ln == 0) { flagB[row] = 1; flag2[row] = 1; }
        int beg = rowPtr[row], end = rowPtr[row + 1];
        for (int j = beg + ln; j < end; j += 16) flag2[pairs[j].x] = 1;
    } else {
        int t = (blockIdx.x - markBlocks) * blockDim.x + threadIdx.x;
        if (t >= batch * EMB) return;
        int b = t >> 6, c = t & 63;
        U[t] = bf2f(emb[users[b] * EMB + c]) * 0.25f;
        I[t] = bf2f(emb[(nUser + items[b]) * EMB + c]) * 0.25f;
    }
}

// ---------- SpMM row body: 8 lanes/row, uint4 = 8 bf16/lane, unroll x4 ----
__device__ __forceinline__ void acc8(float& s0, float& s1, float& s2, float& s3,
                                     float& s4, float& s5, float& s6, float& s7,
                                     float v, uint4 x) {
    s0 += v * bf2f_lo(x.x); s1 += v * bf2f_hi(x.x);
    s2 += v * bf2f_lo(x.y); s3 += v * bf2f_hi(x.y);
    s4 += v * bf2f_lo(x.z); s5 += v * bf2f_hi(x.z);
    s6 += v * bf2f_lo(x.w); s7 += v * bf2f_hi(x.w);
}

__device__ __forceinline__ void spmm_row(const uint4* __restrict__ cur,
                                         uint4* __restrict__ next,
                                         const int* __restrict__ rowPtr,
                                         const int2* __restrict__ pairs,
                                         int row, int fl) {
    int beg = rowPtr[row];
    int end = rowPtr[row + 1];
    float s0 = 0.f, s1 = 0.f, s2 = 0.f, s3 = 0.f;
    float s4 = 0.f, s5 = 0.f, s6 = 0.f, s7 = 0.f;
    int j = beg;
    for (; j + 4 <= end; j += 4) {
        int2 e0 = pairs[j + 0];
        int2 e1 = pairs[j + 1];
        int2 e2 = pairs[j + 2];
        int2 e3 = pairs[j + 3];
        uint4 x0 = cur[(size_t)e0.x * 8 + fl];
        uint4 x1 = cur[(size_t)e1.x * 8 + fl];
        uint4 x2 = cur[(size_t)e2.x * 8 + fl];
        uint4 x3 = cur[(size_t)e3.x * 8 + fl];
        acc8(s0, s1, s2, s3, s4, s5, s6, s7, __int_as_float(e0.y), x0);
        acc8(s0, s1, s2, s3, s4, s5, s6, s7, __int_as_float(e1.y), x1);
        acc8(s0, s1, s2, s3, s4, s5, s6, s7, __int_as_float(e2.y), x2);
        acc8(s0, s1, s2, s3, s4, s5, s6, s7, __int_as_float(e3.y), x3);
    }
    for (; j < end; ++j) {
        int2 e = pairs[j];
        uint4 x = cur[(size_t)e.x * 8 + fl];
        acc8(s0, s1, s2, s3, s4, s5, s6, s7, __int_as_float(e.y), x);
    }
    uint4 o;
    o.x = pack2(s0, s1);
    o.y = pack2(s2, s3);
    o.z = pack2(s4, s5);
    o.w = pack2(s6, s7);
    next[(size_t)row * 8 + fl] = o;
}

__global__ void ALGN_spmm_csr(const uint4* __restrict__ cur, uint4* __restrict__ next,
                              const int* __restrict__ rowPtr, const int2* __restrict__ pairs,
                              int nNodes) {
    int tid = blockIdx.x * blockDim.x + threadIdx.x;
    int row = tid >> 3;
    int fl  = tid & 7;
    if (row >= nNodes) return;
    spmm_row(cur, next, rowPtr, pairs, row, fl);
}

__global__ void ALGN_spmm_flag(const uint4* __restrict__ cur, uint4* __restrict__ next,
                               const int* __restrict__ rowPtr, const int2* __restrict__ pairs,
                               const int* __restrict__ flag, int nNodes) {
    int tid = blockIdx.x * blockDim.x + threadIdx.x;
    int row = tid >> 3;
    int fl  = tid & 7;
    if (row >= nNodes) return;
    if (!flag[row]) return;
    spmm_row(cur, next, rowPtr, pairs, row, fl);
}

// ---------- batch gather-accumulate (layer mean 0.25 folded per side) -----
__global__ void ALGN_gather_add(const unsigned short* __restrict__ emb,
                                const int* __restrict__ users, const int* __restrict__ items,
                                float* __restrict__ U, float* __restrict__ I,
                                int batch, int nUser) {
    int t = blockIdx.x * blockDim.x + threadIdx.x;
    if (t >= batch * EMB) return;
    int b = t >> 6, c = t & 63;
    U[t] += bf2f(emb[users[b] * EMB + c]) * 0.25f;
    I[t] += bf2f(emb[(nUser + items[b]) * EMB + c]) * 0.25f;
}

// ---------- sigmoid(U @ I^T): 32x32 tile, 256 threads, 2x2 out/thread ----
__global__ void ALGN_gemm_sigmoid(const float* __restrict__ U, const float* __restrict__ I,
                                  float* __restrict__ out, int B) {
    __shared__ float su[32][EMB + 1];
    __shared__ float si[32][EMB + 1];
    int tx = threadIdx.x, ty = threadIdx.y;     // 16x16
    int row0 = blockIdx.y * 32, col0 = blockIdx.x * 32;
    int tid = ty * 16 + tx;
    for (int k = tid; k < 32 * EMB; k += 256) {
        int r = k >> 6, c = k & 63;
        su[r][c] = U[(row0 + r) * EMB + c];
        si[r][c] = I[(col0 + r) * EMB + c];
    }
    __syncthreads();
    float s00 = 0.f, s01 = 0.f, s10 = 0.f, s11 = 0.f;
#pragma unroll
    for (int k = 0; k < EMB; ++k) {
        float a0 = su[2 * ty][k],     a1 = su[2 * ty + 1][k];
        float b0 = si[2 * tx][k],     b1 = si[2 * tx + 1][k];
        s00 += a0 * b0; s01 += a0 * b1;
        s10 += a1 * b0; s11 += a1 * b1;
    }
    int r0 = row0 + 2 * ty, c0 = col0 + 2 * tx;
    out[(size_t)r0 * B + c0]           = 1.f / (1.f + __expf(-s00));
    out[(size_t)r0 * B + c0 + 1]       = 1.f / (1.f + __expf(-s01));
    out[(size_t)(r0 + 1) * B + c0]     = 1.f / (1.f + __expf(-s10));
    out[(size_t)(r0 + 1) * B + c0 + 1] = 1.f / (1.f + __expf(-s11));
}

extern "C" void kernel_launch(void* const* d_in, const int* in_sizes, int n_in,
                              void* d_out, int out_size, void* d_ws, size_t ws_size,
                              hipStream_t stream) {
    const float* user_emb = (const float*)d_in[0];
    const float* item_emb = (const float*)d_in[1];
    const float* adj_vals = (const float*)d_in[2];
    const int*   adj_rows = (const int*)d_in[3];
    const int*   adj_cols = (const int*)d_in[4];
    const int*   users    = (const int*)d_in[5];
    const int*   items    = (const int*)d_in[6];
    float* out = (float*)d_out;

    const int nUserF = in_sizes[0];
    const int nItemF = in_sizes[1];
    const int nEdges = in_sizes[2];
    const int batch  = in_sizes[5];
    const int nUser  = nUserF / EMB;
    const int totalF = nUserF + nItemF;
    const int nNodes = totalF / EMB;
    const int n8     = totalF / 8;
    const int nBuckets = (nNodes + BSZ - 1) / BSZ;   // 293
    // seg rounded to x4 so p2's int4/float4 edge loads are 16B-aligned
    const int seg    = (((nEdges + BP - 1) / BP) + 3) & ~3;   // 980

    unsigned short* embA = (unsigned short*)d_ws;
    unsigned short* embB = embA + totalF;
    float* Ub = (float*)(embB + totalF);
    float* Ib = Ub + (size_t)batch * EMB;
    int2*  pairs = (int2*)(Ib + (size_t)batch * EMB);
    int2*  part  = pairs + nEdges;
    int*   rowPtr = (int*)(part + nEdges);
    int*   blockHist   = rowPtr + (nNodes + 1);
    int*   bucketTotal = blockHist + NBMAX * BP;
    int*   bucketBase  = bucketTotal + NBMAX;
    int*   flag2 = bucketBase + (NBMAX + 1);
    int*   flagB = flag2 + nNodes;

    // ---- fused init | p1 ----
    const int initBlocks = (n8 + 255) / 256;         // covers n8 and 2*nNodes flags
    ALGN_init_p1<<<initBlocks + BP, 256, 0, stream>>>(
        (const float4*)user_emb, (const float4*)item_emb, (uint4*)embA,
        flag2, 2 * nNodes, nUserF / 8, n8, initBlocks,
        adj_rows, blockHist, nEdges, seg, nBuckets);

    // ---- deterministic CSR build ----
    ALGN_scanA<<<nBuckets, 1024, 0, stream>>>(blockHist, bucketTotal);
    ALGN_scanB<<<1, 512, 0, stream>>>(bucketTotal, bucketBase, nBuckets);
    ALGN_p2<<<BP, 256, 0, stream>>>(adj_rows, adj_cols, adj_vals,
                                    blockHist, bucketBase, part, nEdges, seg, nBuckets);
    ALGN_bsort<<<nBuckets, 1024, 0, stream>>>(part, bucketBase, pairs, rowPtr,
                                              nNodes, nBuckets, nEdges);

    // ---- fused mark2 | gather_set ----
    const int markBlocks = (2 * batch * 16 + 255) / 256;
    const int gsBlocks   = (batch * EMB + 255) / 256;
    ALGN_mark_gather<<<markBlocks + gsBlocks, 256, 0, stream>>>(
        rowPtr, pairs, users, items, flag2, flagB, batch, nUser, markBlocks,
        embA, Ub, Ib);

    const int fullBlocks = (nNodes * 8 + 255) / 256;

    // ---- layer 1: full ----
    ALGN_spmm_csr<<<fullBlocks, 256, 0, stream>>>(
        (const uint4*)embA, (uint4*)embB, rowPtr, pairs, nNodes);
    ALGN_gather_add<<<(batch * EMB + 255) / 256, 256, 0, stream>>>(
        embB, users, items, Ub, Ib, batch, nUser);

    // ---- layer 2: S2 rows only ----
    ALGN_spmm_flag<<<fullBlocks, 256, 0, stream>>>(
        (const uint4*)embB, (uint4*)embA, rowPtr, pairs, flag2, nNodes);
    ALGN_gather_add<<<(batch * EMB + 255) / 256, 256, 0, stream>>>(
        embA, users, items, Ub, Ib, batch, nUser);

    // ---- layer 3: batch rows only ----
    ALGN_spmm_flag<<<fullBlocks, 256, 0, stream>>>(
        (const uint4*)embA, (uint4*)embB, rowPtr, pairs, flagB, nNodes);
    ALGN_gather_add<<<(batch * EMB + 255) / 256, 256, 0, stream>>>(
        embB, users, items, Ub, Ib, batch, nUser);

    dim3 gg(batch / 32, batch / 32);
    dim3 gb(16, 16);
    ALGN_gemm_sigmoid<<<gg, gb, 0, stream>>>(Ub, Ib, out, batch);
}